// Round 8
// baseline (7295.684 us; speedup 1.0000x reference)
//
#include <hip/hip_runtime.h>
#include <math.h>

#define Bsz 64
#define Tsz 1024
#define Esz 300
#define Hsz 200
#define Gsz 800   // 4*H
#define NTOK (Bsz*Tsz)
#define WPAD 6400

// NOTE: macro params must not collide with float4 member names x/y/z/w
#define FMA4(A_, W_, H_) do { \
  (A_).x = fmaf((W_).x, (H_), (A_).x); \
  (A_).y = fmaf((W_).y, (H_), (A_).y); \
  (A_).z = fmaf((W_).z, (H_), (A_).z); \
  (A_).w = fmaf((W_).w, (H_), (A_).w); } while (0)

// ---------------- lengths: lens[b] = sum(mask[b,:]) ----------------
// mask may be 1-byte bool or 4-byte int. len >= 512 always, so byte[1]
// is 1 iff 1-byte layout.
__global__ __launch_bounds__(256) void k_lengths(const void* __restrict__ mraw,
                                                 int* __restrict__ lens) {
  __shared__ int red[256];
  const unsigned char* mb = (const unsigned char*)mraw;
  const int isbool = (mb[1] != 0);
  int b = blockIdx.x, tid = threadIdx.x;
  int s = 0;
  if (isbool) {
    const unsigned char* row = mb + (size_t)b * Tsz;
    for (int i = tid; i < Tsz; i += 256) s += (row[i] != 0);
  } else {
    const int* row = (const int*)mraw + (size_t)b * Tsz;
    for (int i = tid; i < Tsz; i += 256) s += (row[i] != 0);
  }
  red[tid] = s; __syncthreads();
  for (int off = 128; off; off >>= 1) {
    if (tid < off) red[tid] += red[tid + off];
    __syncthreads();
  }
  if (tid == 0) lens[b] = red[0];
}

// ---------------- Whh transpose: WhhT[j][r] = Whh[r][j] ----------------
__global__ __launch_bounds__(256) void k_transpose(const float* __restrict__ Whh,
                                                   float* __restrict__ WhhT) {
  int idx = blockIdx.x * 256 + threadIdx.x;
  if (idx >= Gsz * Hsz) return;
  int r = idx / Hsz, j = idx - r * Hsz;
  WhhT[(size_t)j * Gsz + r] = Whh[idx];
}

// ---------------- input projection GEMM, both directions (blockIdx.z) --
#define BM 64
#define BN 160
#define BK 20
__global__ __launch_bounds__(256) void k_gemm(const int* __restrict__ x,
                                              const float* __restrict__ embed,
                                              const float* __restrict__ Wf,
                                              const float* __restrict__ biasf,
                                              const float* __restrict__ Wb_,
                                              const float* __restrict__ biasb,
                                              float* __restrict__ Pf,
                                              float* __restrict__ Pb,
                                              int t0f, int t0b, int tcShift) {
  __shared__ __align__(16) float As[BK][BM];
  __shared__ __align__(16) float Bs[BK][BN];
  __shared__ int toks[BM];
  const int revz = blockIdx.z;
  const float* __restrict__ W    = revz ? Wb_  : Wf;
  const float* __restrict__ bias = revz ? biasb : biasf;
  float* __restrict__ P          = revz ? Pb   : Pf;
  const int t0                   = revz ? t0b  : t0f;
  int tid = threadIdx.x;
  int n0 = blockIdx.x * BM;
  int j0 = blockIdx.y * BN;
  if (tid < BM) {
    int n = n0 + tid;
    int bb = n >> tcShift;
    int tl = n & ((1 << tcShift) - 1);
    toks[tid] = x[(bb << 10) + t0 + tl];
  }
  float acc[8][5];
#pragma unroll
  for (int i = 0; i < 8; i++)
#pragma unroll
    for (int j = 0; j < 5; j++) acc[i][j] = 0.f;
  int rg = tid >> 5;
  int cg = tid & 31;
  for (int k0 = 0; k0 < Esz; k0 += BK) {
    __syncthreads();
    for (int idx = tid; idx < BM * 5; idx += 256) {
      int r = idx / 5, q = idx % 5;
      const float4 v = *reinterpret_cast<const float4*>(
          embed + (size_t)toks[r] * Esz + k0 + q * 4);
      As[q * 4 + 0][r] = v.x; As[q * 4 + 1][r] = v.y;
      As[q * 4 + 2][r] = v.z; As[q * 4 + 3][r] = v.w;
    }
    for (int idx = tid; idx < BN * 5; idx += 256) {
      int j = idx / 5, q = idx % 5;
      const float4 v = *reinterpret_cast<const float4*>(
          W + (size_t)(j0 + j) * Esz + k0 + q * 4);
      Bs[q * 4 + 0][j] = v.x; Bs[q * 4 + 1][j] = v.y;
      Bs[q * 4 + 2][j] = v.z; Bs[q * 4 + 3][j] = v.w;
    }
    __syncthreads();
#pragma unroll
    for (int kk = 0; kk < BK; ++kk) {
      float4 a0 = *reinterpret_cast<const float4*>(&As[kk][rg * 8]);
      float4 a1 = *reinterpret_cast<const float4*>(&As[kk][rg * 8 + 4]);
      float a[8] = {a0.x, a0.y, a0.z, a0.w, a1.x, a1.y, a1.z, a1.w};
      float bv[5];
#pragma unroll
      for (int j = 0; j < 5; j++) bv[j] = Bs[kk][cg + 32 * j];
#pragma unroll
      for (int i = 0; i < 8; i++)
#pragma unroll
        for (int j = 0; j < 5; j++) acc[i][j] = fmaf(a[i], bv[j], acc[i][j]);
    }
  }
#pragma unroll
  for (int j = 0; j < 5; j++) {
    int col = j0 + cg + 32 * j;
    float bb = bias[col];
#pragma unroll
    for (int i = 0; i < 8; i++) {
      int n = n0 + rg * 8 + i;
      P[(size_t)n * Gsz + col] = acc[i][j] + bb;
    }
  }
}

// ---------------- masked LSTM, weights CU-resident ---------------------
// 128 WGs (bid<64 fwd, else bwd), 512 threads (8 waves). Workers tid<500:
// col = tid%100 owns gate-row float4 pair {2col, 2col+1}; gk = tid/100 owns
// k-slice [40gk, 40gk+40). Weight split per worker (80 float4 total):
//   u in [0,24):  48 f4 persistent in VGPR (192 regs, loaded once)
//   u in [24,32): 16 f4 persistent in LDS  (125 KB, [i][tid] layout)
//   u in [32,40): 16 f4 streamed per step  (128 KB/step, 8-deep ring)
__global__ __launch_bounds__(512, 2) void k_lstm(
    const float* __restrict__ Pf, const float* __restrict__ Pb,
    const float* __restrict__ WhhTf, const float* __restrict__ WhhTb,
    const int* __restrict__ lens,
    const float* __restrict__ Wa, const float* __restrict__ Wb,
    float* __restrict__ hcF, float* __restrict__ hcB,
    float* __restrict__ zaf, float* __restrict__ zbf,
    float* __restrict__ zab, float* __restrict__ zbb,
    int t0f, int t0b, int TC, int init) {
  __shared__ __align__(16) float h[Hsz];
  __shared__ __align__(16) float c[Hsz];
  __shared__ __align__(16) float4 g4[200];      // gates as 200 float4
  __shared__ __align__(16) float4 part[1000];   // [gk][200]
  __shared__ __align__(16) float4 wlds[8000];   // [16][500] resident weights
  __shared__ float redA[4], redB[4];
  __shared__ float zaL[Tsz], zbL[Tsz];
  int bid = blockIdx.x, tid = threadIdx.x;
  int rev = bid >> 6;
  int b = bid & 63;
  int len = lens[b];
  const float* P    = rev ? Pb : Pf;
  const float* WhhT = rev ? WhhTb : WhhTf;
  float* hcb = (rev ? hcB : hcF) + (size_t)b * 2 * Hsz;
  float* za  = rev ? zab : zaf;
  float* zb  = rev ? zbb : zbf;
  int t0 = rev ? t0b : t0f;
  float wa = 0.f, wb = 0.f;
  if (tid < Hsz) {
    h[tid] = init ? 0.f : hcb[tid];
    c[tid] = init ? 0.f : hcb[Hsz + tid];
    int off = rev ? Hsz : 0;
    wa = Wa[off + tid]; wb = Wb[off + tid];
  }
  const int worker = (tid < 500);
  int col = 0, gk = 0;
  if (worker) { col = tid % 100; gk = tid / 100; }
  const int hbase = gk * 40;
  const float4* __restrict__ wp4 =
      reinterpret_cast<const float4*>(WhhT) + (size_t)hbase * 200 + 2 * col;

  // ---- load persistent weights (once per dispatch) ----
  float4 wreg[48];
  if (worker) {
#pragma unroll
    for (int u = 0; u < 24; u++) {
      wreg[2 * u]     = wp4[u * 200];
      wreg[2 * u + 1] = wp4[u * 200 + 1];
    }
#pragma unroll
    for (int i = 0; i < 16; i++) {          // u = 24 + (i>>1), p = i&1
      wlds[i * 500 + tid] = wp4[(24 + (i >> 1)) * 200 + (i & 1)];
    }
  }
  __syncthreads();

  int lo = t0;
  int hi = t0 + TC; if (len < hi) hi = len;
  int nsteps = hi - lo; if (nsteps < 0) nsteps = 0;
  const float4* __restrict__ wps = wp4 + 32 * 200;   // streamed region

  for (int s = 0; s < nsteps; ++s) {
    int t = rev ? (hi - 1 - s) : (lo + s);
    const float4* __restrict__ Prow4 = reinterpret_cast<const float4*>(
        P + ((size_t)b * TC + (t - t0)) * Gsz);
    if (worker) {
      // issue all 8 ring slots early (in flight during VGPR/LDS fmas)
      float4 rbuf[8];
#pragma unroll
      for (int q = 0; q < 8; q++) rbuf[q] = wps[(q >> 1) * 200 + (q & 1)];
      float4 acc0, acc1;
      if (gk == 0) { acc0 = Prow4[2 * col]; acc1 = Prow4[2 * col + 1]; }
      else {
        acc0.x = acc0.y = acc0.z = acc0.w = 0.f;
        acc1.x = acc1.y = acc1.z = acc1.w = 0.f;
      }
      // phase 1: VGPR-resident weights, u in [0,24)
#pragma unroll
      for (int u = 0; u < 24; u++) {
        float hj = h[hbase + u];
        FMA4(acc0, wreg[2 * u], hj);
        FMA4(acc1, wreg[2 * u + 1], hj);
      }
      // phase 2: LDS-resident weights, u in [24,32)
#pragma unroll
      for (int i = 0; i < 8; i++) {
        float hj = h[hbase + 24 + i];
        float4 w0 = wlds[(2 * i) * 500 + tid];
        float4 w1 = wlds[(2 * i + 1) * 500 + tid];
        FMA4(acc0, w0, hj);
        FMA4(acc1, w1, hj);
      }
      // phase 3: streamed weights, u in [32,40), 8-deep static ring
#pragma unroll
      for (int q = 0; q < 8; q++) {
        float4 wv = rbuf[q];
        rbuf[q] = wps[((q + 8) >> 1) * 200 + ((q + 8) & 1)];
        float hj = h[hbase + 32 + (q >> 1)];
        if (q & 1) { FMA4(acc1, wv, hj); } else { FMA4(acc0, wv, hj); }
      }
#pragma unroll
      for (int q = 8; q < 16; q++) {
        float4 wv = rbuf[q & 7];
        float hj = h[hbase + 32 + (q >> 1)];
        if (q & 1) { FMA4(acc1, wv, hj); } else { FMA4(acc0, wv, hj); }
      }
      part[gk * 200 + 2 * col]     = acc0;
      part[gk * 200 + 2 * col + 1] = acc1;
    }
    __syncthreads();   // partials ready; h reads complete
    if (tid < 200) {
      float4 p0 = part[tid],       p1 = part[200 + tid], p2 = part[400 + tid];
      float4 p3 = part[600 + tid], p4 = part[800 + tid];
      float4 gg;
      gg.x = p0.x + p1.x + p2.x + p3.x + p4.x;
      gg.y = p0.y + p1.y + p2.y + p3.y + p4.y;
      gg.z = p0.z + p1.z + p2.z + p3.z + p4.z;
      gg.w = p0.w + p1.w + p2.w + p3.w + p4.w;
      g4[tid] = gg;
    }
    __syncthreads();   // g ready
    float pa = 0.f, pb = 0.f;
    if (tid < Hsz) {
      const float* g = reinterpret_cast<const float*>(g4);
      float gi = g[tid], gf = g[Hsz + tid];
      float gc = g[2 * Hsz + tid], go = g[3 * Hsz + tid];
      float ig = 1.f / (1.f + expf(-gi));
      float fg = 1.f / (1.f + expf(-gf));
      float gt = tanhf(gc);
      float og = 1.f / (1.f + expf(-go));
      float cn = fmaf(fg, c[tid], ig * gt);
      float hn = og * tanhf(cn);
      c[tid] = cn; h[tid] = hn;
      pa = hn * wa; pb = hn * wb;
    }
#pragma unroll
    for (int off = 32; off; off >>= 1) {
      pa += __shfl_down(pa, off);
      pb += __shfl_down(pb, off);
    }
    if ((tid & 63) == 0 && tid < 256) { redA[tid >> 6] = pa; redB[tid >> 6] = pb; }
    __syncthreads();   // redA/B ready; h writes visible for next step
    if (tid == 0) {
      float sa = 0.f, sb = 0.f;
#pragma unroll
      for (int w = 0; w < 4; ++w) { sa += redA[w]; sb += redB[w]; }
      zaL[s] = sa; zbL[s] = sb;
    }
  }
  __syncthreads();
  if (tid < Hsz) { hcb[tid] = h[tid]; hcb[Hsz + tid] = c[tid]; }
  for (int s = tid; s < nsteps; s += 512) {
    int t = rev ? (hi - 1 - s) : (lo + s);
    za[(size_t)b * Tsz + t] = zaL[s];
    zb[(size_t)b * Tsz + t] = zbL[s];
  }
}

// ---------------- Kuma head per token (double precision) ---------------
__global__ __launch_bounds__(256) void k_head(const float* __restrict__ zaf,
                                              const float* __restrict__ zbf,
                                              const float* __restrict__ zab,
                                              const float* __restrict__ zbb,
                                              const int* __restrict__ lens,
                                              const float* __restrict__ ba,
                                              const float* __restrict__ bb,
                                              float* __restrict__ zp) {
  int n = blockIdx.x * 256 + threadIdx.x;
  if (n >= NTOK) return;
  int b = n >> 10, t = n & 1023;
  if (t >= lens[b]) { zp[n] = 0.f; return; }
  double av = ((double)zaf[n] + (double)zab[n]) * 100.0 + (double)ba[0];
  double bv = ((double)zbf[n] + (double)zbb[n]) * 100.0 + (double)bb[0];
  double a  = av > 0.0 ? av + log1p(exp(-av)) : log1p(exp(av));
  double bk = bv > 0.0 ? bv + log1p(exp(-bv)) : log1p(exp(bv));
  a  = fmin(fmax(a, 1e-6), 100.0);
  bk = fmin(fmax(bk, 1e-6), 100.0);
  double ia = 1.0 + 1.0 / a;
  double lb = lgamma(ia) + lgamma(bk) - lgamma(ia + bk);
  double mean = bk * exp(lb);
  mean = -0.1 + 1.2 * mean;
  mean = fmin(fmax(mean, 0.0), 1.0);
  zp[n] = (float)mean;
}

// ---------------- stable top-k selection per row -----------------------
__global__ __launch_bounds__(256) void k_select(const float* __restrict__ zp,
                                                const int* __restrict__ lens,
                                                float* __restrict__ out) {
  __shared__ float zv[Tsz];
  __shared__ float wbv[4];
  __shared__ int wbi[4];
  __shared__ int stop;
  int b = blockIdx.x, tid = threadIdx.x;
  const float* row = zp + (size_t)b * Tsz;
  for (int i = tid; i < Tsz; i += 256) zv[i] = row[i];
  if (tid == 0) stop = 0;
  int len = lens[b];
  int k = (int)rintf(0.1f * (float)len);
  __syncthreads();
  for (int it = 0; it < k; ++it) {
    float bvl = -1.f; int bil = 0;
#pragma unroll
    for (int s = 0; s < 4; s++) {
      int i = tid * 4 + s;
      float v = zv[i];
      if (v > bvl) { bvl = v; bil = i; }
    }
    for (int off = 32; off; off >>= 1) {
      float ov = __shfl_down(bvl, off);
      int   oi = __shfl_down(bil, off);
      if (ov > bvl || (ov == bvl && oi < bil)) { bvl = ov; bil = oi; }
    }
    int w = tid >> 6;
    if ((tid & 63) == 0) { wbv[w] = bvl; wbi[w] = bil; }
    __syncthreads();
    if (tid == 0) {
      float fb = wbv[0]; int fi = wbi[0];
      for (int q = 1; q < 4; q++)
        if (wbv[q] > fb || (wbv[q] == fb && wbi[q] < fi)) { fb = wbv[q]; fi = wbi[q]; }
      if (fb <= 0.f) stop = 1;
      else { out[(size_t)b * Tsz + fi] = 1.0f; zv[fi] = -1e30f; }
    }
    __syncthreads();
    if (stop) break;
  }
}

extern "C" void kernel_launch(void* const* d_in, const int* in_sizes, int n_in,
                              void* d_out, int out_size, void* d_ws, size_t ws_size,
                              hipStream_t stream) {
  const int*   x      = (const int*)d_in[0];
  const void*  mask   = d_in[1];
  const float* embed  = (const float*)d_in[2];
  const float* Wih_f  = (const float*)d_in[3];
  const float* Whh_f  = (const float*)d_in[4];
  const float* b_f    = (const float*)d_in[5];
  const float* Wih_b  = (const float*)d_in[6];
  const float* Whh_b  = (const float*)d_in[7];
  const float* b_b    = (const float*)d_in[8];
  const float* Wa     = (const float*)d_in[9];
  const float* ba     = (const float*)d_in[10];
  const float* Wb     = (const float*)d_in[11];
  const float* bb     = (const float*)d_in[12];
  float* out = (float*)d_out;

  // ---- adaptive time-chunk: need TWO P buffers (fwd + bwd) ----
  size_t fixedBytes = (5 * (size_t)NTOK + 2 * (size_t)Bsz * 2 * Hsz +
                       2 * ((size_t)Hsz * Gsz + WPAD)) * sizeof(float) +
                      Bsz * sizeof(int) + 1024;
  int TC = 16;
  const int cand[7] = {1024, 512, 256, 128, 64, 32, 16};
  for (int i = 0; i < 7; i++) {
    size_t need = fixedBytes + 2 * (size_t)Bsz * cand[i] * Gsz * sizeof(float);
    if (need <= ws_size) { TC = cand[i]; break; }
  }
  int tcShift = 31 - __builtin_clz((unsigned)TC);

  float* Pf    = (float*)d_ws;                      // Bsz*TC*Gsz
  float* Pb    = Pf + (size_t)Bsz * TC * Gsz;       // Bsz*TC*Gsz
  float* zaf   = Pb + (size_t)Bsz * TC * Gsz;       // NTOK
  float* zbf   = zaf + NTOK;
  float* zab   = zbf + NTOK;
  float* zbb   = zab + NTOK;
  float* zp    = zbb + NTOK;
  float* hcF   = zp + NTOK;                         // Bsz*2*Hsz
  float* hcB   = hcF + (size_t)Bsz * 2 * Hsz;
  float* WhhTf = hcB + (size_t)Bsz * 2 * Hsz;       // Hsz*Gsz + WPAD
  float* WhhTb = WhhTf + (size_t)Hsz * Gsz + WPAD;
  int*   lens  = (int*)(WhhTb + (size_t)Hsz * Gsz + WPAD);

  k_lengths<<<Bsz, 256, 0, stream>>>(mask, lens);

  const int tgrid = (Gsz * Hsz + 255) / 256;
  k_transpose<<<tgrid, 256, 0, stream>>>(Whh_f, WhhTf);
  k_transpose<<<tgrid, 256, 0, stream>>>(Whh_b, WhhTb);

  int nch = Tsz / TC;
  dim3 gg((Bsz * TC) / BM, Gsz / BN, 2);
  for (int ci = 0; ci < nch; ++ci) {
    int t0f = ci * TC;
    int t0b = (nch - 1 - ci) * TC;
    k_gemm<<<gg, 256, 0, stream>>>(x, embed, Wih_f, b_f, Wih_b, b_b,
                                   Pf, Pb, t0f, t0b, tcShift);
    k_lstm<<<2 * Bsz, 512, 0, stream>>>(Pf, Pb, WhhTf, WhhTb, lens, Wa, Wb,
                                        hcF, hcB, zaf, zbf, zab, zbb,
                                        t0f, t0b, TC, ci == 0);
  }

  k_head<<<NTOK / 256, 256, 0, stream>>>(zaf, zbf, zab, zbb, lens, ba, bb, zp);

  (void)hipMemsetAsync(d_out, 0, (size_t)out_size * sizeof(float), stream);
  k_select<<<Bsz, 256, 0, stream>>>(zp, lens, out);
}

// Round 9
// 6976.631 us; speedup vs baseline: 1.0457x; 1.0457x over previous
//
#include <hip/hip_runtime.h>
#include <math.h>

#define Bsz 64
#define Tsz 1024
#define Esz 300
#define Hsz 200
#define Gsz 800   // 4*H
#define NTOK (Bsz*Tsz)
#define WPAD 6400

// NOTE: macro params must not collide with float4 member names x/y/z/w
#define FMA4(A_, W_, H_) do { \
  (A_).x = fmaf((W_).x, (H_), (A_).x); \
  (A_).y = fmaf((W_).y, (H_), (A_).y); \
  (A_).z = fmaf((W_).z, (H_), (A_).z); \
  (A_).w = fmaf((W_).w, (H_), (A_).w); } while (0)

// ---------------- lengths: lens[b] = sum(mask[b,:]) ----------------
__global__ __launch_bounds__(256) void k_lengths(const void* __restrict__ mraw,
                                                 int* __restrict__ lens) {
  __shared__ int red[256];
  const unsigned char* mb = (const unsigned char*)mraw;
  const int isbool = (mb[1] != 0);
  int b = blockIdx.x, tid = threadIdx.x;
  int s = 0;
  if (isbool) {
    const unsigned char* row = mb + (size_t)b * Tsz;
    for (int i = tid; i < Tsz; i += 256) s += (row[i] != 0);
  } else {
    const int* row = (const int*)mraw + (size_t)b * Tsz;
    for (int i = tid; i < Tsz; i += 256) s += (row[i] != 0);
  }
  red[tid] = s; __syncthreads();
  for (int off = 128; off; off >>= 1) {
    if (tid < off) red[tid] += red[tid + off];
    __syncthreads();
  }
  if (tid == 0) lens[b] = red[0];
}

// ---------------- Whh transpose: WhhT[j][r] = Whh[r][j] ----------------
__global__ __launch_bounds__(256) void k_transpose(const float* __restrict__ Whh,
                                                   float* __restrict__ WhhT) {
  int idx = blockIdx.x * 256 + threadIdx.x;
  if (idx >= Gsz * Hsz) return;
  int r = idx / Hsz, j = idx - r * Hsz;
  WhhT[(size_t)j * Gsz + r] = Whh[idx];
}

// ---------------- input projection GEMM, both directions (blockIdx.z) --
#define BM 64
#define BN 160
#define BK 20
__global__ __launch_bounds__(256) void k_gemm(const int* __restrict__ x,
                                              const float* __restrict__ embed,
                                              const float* __restrict__ Wf,
                                              const float* __restrict__ biasf,
                                              const float* __restrict__ Wb_,
                                              const float* __restrict__ biasb,
                                              float* __restrict__ Pf,
                                              float* __restrict__ Pb,
                                              int t0f, int t0b, int tcShift) {
  __shared__ __align__(16) float As[BK][BM];
  __shared__ __align__(16) float Bs[BK][BN];
  __shared__ int toks[BM];
  const int revz = blockIdx.z;
  const float* __restrict__ W    = revz ? Wb_  : Wf;
  const float* __restrict__ bias = revz ? biasb : biasf;
  float* __restrict__ P          = revz ? Pb   : Pf;
  const int t0                   = revz ? t0b  : t0f;
  int tid = threadIdx.x;
  int n0 = blockIdx.x * BM;
  int j0 = blockIdx.y * BN;
  if (tid < BM) {
    int n = n0 + tid;
    int bb = n >> tcShift;
    int tl = n & ((1 << tcShift) - 1);
    toks[tid] = x[(bb << 10) + t0 + tl];
  }
  float acc[8][5];
#pragma unroll
  for (int i = 0; i < 8; i++)
#pragma unroll
    for (int j = 0; j < 5; j++) acc[i][j] = 0.f;
  int rg = tid >> 5;
  int cg = tid & 31;
  for (int k0 = 0; k0 < Esz; k0 += BK) {
    __syncthreads();
    for (int idx = tid; idx < BM * 5; idx += 256) {
      int r = idx / 5, q = idx % 5;
      const float4 v = *reinterpret_cast<const float4*>(
          embed + (size_t)toks[r] * Esz + k0 + q * 4);
      As[q * 4 + 0][r] = v.x; As[q * 4 + 1][r] = v.y;
      As[q * 4 + 2][r] = v.z; As[q * 4 + 3][r] = v.w;
    }
    for (int idx = tid; idx < BN * 5; idx += 256) {
      int j = idx / 5, q = idx % 5;
      const float4 v = *reinterpret_cast<const float4*>(
          W + (size_t)(j0 + j) * Esz + k0 + q * 4);
      Bs[q * 4 + 0][j] = v.x; Bs[q * 4 + 1][j] = v.y;
      Bs[q * 4 + 2][j] = v.z; Bs[q * 4 + 3][j] = v.w;
    }
    __syncthreads();
#pragma unroll
    for (int kk = 0; kk < BK; ++kk) {
      float4 a0 = *reinterpret_cast<const float4*>(&As[kk][rg * 8]);
      float4 a1 = *reinterpret_cast<const float4*>(&As[kk][rg * 8 + 4]);
      float a[8] = {a0.x, a0.y, a0.z, a0.w, a1.x, a1.y, a1.z, a1.w};
      float bv[5];
#pragma unroll
      for (int j = 0; j < 5; j++) bv[j] = Bs[kk][cg + 32 * j];
#pragma unroll
      for (int i = 0; i < 8; i++)
#pragma unroll
        for (int j = 0; j < 5; j++) acc[i][j] = fmaf(a[i], bv[j], acc[i][j]);
    }
  }
#pragma unroll
  for (int j = 0; j < 5; j++) {
    int col = j0 + cg + 32 * j;
    float bb = bias[col];
#pragma unroll
    for (int i = 0; i < 8; i++) {
      int n = n0 + rg * 8 + i;
      P[(size_t)n * Gsz + col] = acc[i][j] + bb;
    }
  }
}

// ---------------- masked LSTM, pair-split, weights fully CU-resident ----
// 256 WGs: bid = half*128 + dir*64 + b. Half owns gate rows
// [half*400, half*400+400) = 100 float4 columns of WhhT. 512 threads,
// 500 workers: col = tid%100 (one f4 col), gk = tid/100 (k-slice of 40).
// Per-worker 40 f4 weights: 32 in VGPR + 8 in LDS -> ZERO streaming.
// Per step the halves exchange 400 pre-activation floats via global xbuf
// (parity double-buffer) with value-flags (monotone step ordinal),
// release/acquire agent-scope atomics. Both halves compute identical h,c.
__global__ __launch_bounds__(512, 2) void k_lstm(
    const float* __restrict__ Pf, const float* __restrict__ Pb,
    const float* __restrict__ WhhTf, const float* __restrict__ WhhTb,
    const int* __restrict__ lens,
    const float* __restrict__ Wa, const float* __restrict__ Wb,
    float* __restrict__ hcF, float* __restrict__ hcB,
    float* __restrict__ zaf, float* __restrict__ zbf,
    float* __restrict__ zab, float* __restrict__ zbb,
    float4* __restrict__ xbuf, int* __restrict__ flags,
    int t0f, int t0b, int TC, int init) {
  __shared__ __align__(16) float h[Hsz];
  __shared__ __align__(16) float c[Hsz];
  __shared__ __align__(16) float4 part[500];    // [gk][col]
  __shared__ __align__(16) float4 ownv[100];    // this half's reduced gates
  __shared__ __align__(16) float4 wlds[4000];   // [8][500] resident weights
  __shared__ float redA[4], redB[4];
  __shared__ float zaL[Tsz], zbL[Tsz];
  int bid = blockIdx.x, tid = threadIdx.x;
  int half = bid >> 7;
  int rev  = (bid >> 6) & 1;
  int b    = bid & 63;
  int len = lens[b];
  const float* P    = rev ? Pb : Pf;
  const float* WhhT = rev ? WhhTb : WhhTf;
  float* hcb = (rev ? hcB : hcF) + (size_t)b * 2 * Hsz;
  float* za  = rev ? zab : zaf;
  float* zb  = rev ? zbb : zbf;
  int t0 = rev ? t0b : t0f;

  int pairid  = rev * 64 + b;
  int selfIdx = pairid * 2 + half;
  int peerIdx = pairid * 2 + (half ^ 1);
  float4* xb_self = xbuf + (size_t)selfIdx * 200;          // 2 parity x 100 f4
  float*  xb_peer = (float*)(xbuf + (size_t)peerIdx * 200);
  int* flag_self = flags + selfIdx;
  int* flag_peer = flags + peerIdx;

  float wa = 0.f, wb = 0.f;
  if (tid < Hsz) {
    h[tid] = init ? 0.f : hcb[tid];
    c[tid] = init ? 0.f : hcb[Hsz + tid];
    int off = rev ? Hsz : 0;
    wa = Wa[off + tid]; wb = Wb[off + tid];
  }
  const int worker = (tid < 500);
  int col = 0, gk = 0;
  if (worker) { col = tid % 100; gk = tid / 100; }
  const int hbase = gk * 40;
  // weight f4 pointer: rows j in [40gk,40gk+40), f4-col (half*100+col)
  const float4* __restrict__ wp4 =
      reinterpret_cast<const float4*>(WhhT) + (size_t)hbase * 200 +
      half * 100 + col;

  // ---- load ALL weights resident (once per dispatch) ----
  float4 wreg[32];
  if (worker) {
#pragma unroll
    for (int u = 0; u < 32; u++) wreg[u] = wp4[u * 200];
#pragma unroll
    for (int i = 0; i < 8; i++) wlds[i * 500 + tid] = wp4[(32 + i) * 200];
  }
  __syncthreads();

  int lo = t0;
  int hi = t0 + TC; if (len < hi) hi = len;
  int nsteps = hi - lo; if (nsteps < 0) nsteps = 0;
  // steps completed in earlier chunks (same for both halves)
  int done = rev ? (len - hi) : (t0 < len ? t0 : len);
  if (done < 0) done = 0;

  for (int s = 0; s < nsteps; ++s) {
    int t = rev ? (hi - 1 - s) : (lo + s);
    int ord = done + s + 1;          // monotone step ordinal, >=1
    int par = ord & 1;
    const float4* __restrict__ Prow4 = reinterpret_cast<const float4*>(
        P + ((size_t)b * TC + (t - t0)) * Gsz) + half * 100;
    if (worker) {
      float4 acc;
      if (gk == 0) acc = Prow4[col];
      else { acc.x = 0.f; acc.y = 0.f; acc.z = 0.f; acc.w = 0.f; }
#pragma unroll
      for (int u = 0; u < 32; u++) {
        float hj = h[hbase + u];
        FMA4(acc, wreg[u], hj);
      }
#pragma unroll
      for (int i = 0; i < 8; i++) {
        float hj = h[hbase + 32 + i];
        float4 wv = wlds[i * 500 + tid];
        FMA4(acc, wv, hj);
      }
      part[tid] = acc;
    }
    __syncthreads();   // partials ready
    if (tid < 100) {
      float4 p0 = part[tid],       p1 = part[100 + tid], p2 = part[200 + tid];
      float4 p3 = part[300 + tid], p4 = part[400 + tid];
      float4 sv;
      sv.x = p0.x + p1.x + p2.x + p3.x + p4.x;
      sv.y = p0.y + p1.y + p2.y + p3.y + p4.y;
      sv.z = p0.z + p1.z + p2.z + p3.z + p4.z;
      sv.w = p0.w + p1.w + p2.w + p3.w + p4.w;
      ownv[tid] = sv;
      xb_self[par * 100 + tid] = sv;     // publish our 400 gate floats
    }
    __syncthreads();   // xb_self writes + ownv done block-wide
    if (tid == 0) {
      __hip_atomic_store(flag_self, ord, __ATOMIC_RELEASE,
                         __HIP_MEMORY_SCOPE_AGENT);
      while (__hip_atomic_load(flag_peer, __ATOMIC_ACQUIRE,
                               __HIP_MEMORY_SCOPE_AGENT) < ord) { }
    }
    __syncthreads();   // peer data now visible (acquire + barrier)
    float pa = 0.f, pb = 0.f;
    if (tid < Hsz) {
      const float* ownf = reinterpret_cast<const float*>(ownv);
      float o0 = ownf[tid], o1 = ownf[200 + tid];
      float* pf = xb_peer + par * 400;
      // agent-scope coherent reads (correct regardless of XCD placement)
      float p0 = __hip_atomic_load(pf + tid, __ATOMIC_RELAXED,
                                   __HIP_MEMORY_SCOPE_AGENT);
      float p1 = __hip_atomic_load(pf + 200 + tid, __ATOMIC_RELAXED,
                                   __HIP_MEMORY_SCOPE_AGENT);
      float gi, gf, gc, go;
      if (half == 0) { gi = o0; gf = o1; gc = p0; go = p1; }
      else           { gi = p0; gf = p1; gc = o0; go = o1; }
      float ig = 1.f / (1.f + expf(-gi));
      float fg = 1.f / (1.f + expf(-gf));
      float gt = tanhf(gc);
      float og = 1.f / (1.f + expf(-go));
      float cn = fmaf(fg, c[tid], ig * gt);
      float hn = og * tanhf(cn);
      c[tid] = cn; h[tid] = hn;
      if (half == 0) { pa = hn * wa; pb = hn * wb; }
    }
#pragma unroll
    for (int off = 32; off; off >>= 1) {
      pa += __shfl_down(pa, off);
      pb += __shfl_down(pb, off);
    }
    if ((tid & 63) == 0 && tid < 256) { redA[tid >> 6] = pa; redB[tid >> 6] = pb; }
    __syncthreads();   // h/c + red ready for next step
    if (tid == 0 && half == 0) {
      float sa = 0.f, sb = 0.f;
#pragma unroll
      for (int w = 0; w < 4; ++w) { sa += redA[w]; sb += redB[w]; }
      zaL[s] = sa; zbL[s] = sb;
    }
  }
  __syncthreads();
  if (half == 0) {
    if (tid < Hsz) { hcb[tid] = h[tid]; hcb[Hsz + tid] = c[tid]; }
    for (int s = tid; s < nsteps; s += 512) {
      int t = rev ? (hi - 1 - s) : (lo + s);
      za[(size_t)b * Tsz + t] = zaL[s];
      zb[(size_t)b * Tsz + t] = zbL[s];
    }
  }
}

// ---------------- Kuma head per token (double precision) ---------------
__global__ __launch_bounds__(256) void k_head(const float* __restrict__ zaf,
                                              const float* __restrict__ zbf,
                                              const float* __restrict__ zab,
                                              const float* __restrict__ zbb,
                                              const int* __restrict__ lens,
                                              const float* __restrict__ ba,
                                              const float* __restrict__ bb,
                                              float* __restrict__ zp) {
  int n = blockIdx.x * 256 + threadIdx.x;
  if (n >= NTOK) return;
  int b = n >> 10, t = n & 1023;
  if (t >= lens[b]) { zp[n] = 0.f; return; }
  double av = ((double)zaf[n] + (double)zab[n]) * 100.0 + (double)ba[0];
  double bv = ((double)zbf[n] + (double)zbb[n]) * 100.0 + (double)bb[0];
  double a  = av > 0.0 ? av + log1p(exp(-av)) : log1p(exp(av));
  double bk = bv > 0.0 ? bv + log1p(exp(-bv)) : log1p(exp(bv));
  a  = fmin(fmax(a, 1e-6), 100.0);
  bk = fmin(fmax(bk, 1e-6), 100.0);
  double ia = 1.0 + 1.0 / a;
  double lb = lgamma(ia) + lgamma(bk) - lgamma(ia + bk);
  double mean = bk * exp(lb);
  mean = -0.1 + 1.2 * mean;
  mean = fmin(fmax(mean, 0.0), 1.0);
  zp[n] = (float)mean;
}

// ---------------- stable top-k selection per row -----------------------
__global__ __launch_bounds__(256) void k_select(const float* __restrict__ zp,
                                                const int* __restrict__ lens,
                                                float* __restrict__ out) {
  __shared__ float zv[Tsz];
  __shared__ float wbv[4];
  __shared__ int wbi[4];
  __shared__ int stop;
  int b = blockIdx.x, tid = threadIdx.x;
  const float* row = zp + (size_t)b * Tsz;
  for (int i = tid; i < Tsz; i += 256) zv[i] = row[i];
  if (tid == 0) stop = 0;
  int len = lens[b];
  int k = (int)rintf(0.1f * (float)len);
  __syncthreads();
  for (int it = 0; it < k; ++it) {
    float bvl = -1.f; int bil = 0;
#pragma unroll
    for (int s = 0; s < 4; s++) {
      int i = tid * 4 + s;
      float v = zv[i];
      if (v > bvl) { bvl = v; bil = i; }
    }
    for (int off = 32; off; off >>= 1) {
      float ov = __shfl_down(bvl, off);
      int   oi = __shfl_down(bil, off);
      if (ov > bvl || (ov == bvl && oi < bil)) { bvl = ov; bil = oi; }
    }
    int w = tid >> 6;
    if ((tid & 63) == 0) { wbv[w] = bvl; wbi[w] = bil; }
    __syncthreads();
    if (tid == 0) {
      float fb = wbv[0]; int fi = wbi[0];
      for (int q = 1; q < 4; q++)
        if (wbv[q] > fb || (wbv[q] == fb && wbi[q] < fi)) { fb = wbv[q]; fi = wbi[q]; }
      if (fb <= 0.f) stop = 1;
      else { out[(size_t)b * Tsz + fi] = 1.0f; zv[fi] = -1e30f; }
    }
    __syncthreads();
    if (stop) break;
  }
}

extern "C" void kernel_launch(void* const* d_in, const int* in_sizes, int n_in,
                              void* d_out, int out_size, void* d_ws, size_t ws_size,
                              hipStream_t stream) {
  const int*   x      = (const int*)d_in[0];
  const void*  mask   = d_in[1];
  const float* embed  = (const float*)d_in[2];
  const float* Wih_f  = (const float*)d_in[3];
  const float* Whh_f  = (const float*)d_in[4];
  const float* b_f    = (const float*)d_in[5];
  const float* Wih_b  = (const float*)d_in[6];
  const float* Whh_b  = (const float*)d_in[7];
  const float* b_b    = (const float*)d_in[8];
  const float* Wa     = (const float*)d_in[9];
  const float* ba     = (const float*)d_in[10];
  const float* Wb     = (const float*)d_in[11];
  const float* bb     = (const float*)d_in[12];
  float* out = (float*)d_out;

  // xbuf: 128 pairs x 2 halves x 2 parity x 100 float4 = 409600 floats
  const size_t XBUF_F = (size_t)128 * 2 * 2 * 100 * 4;
  // ---- adaptive time-chunk: need TWO P buffers (fwd + bwd) ----
  size_t fixedBytes = (5 * (size_t)NTOK + 2 * (size_t)Bsz * 2 * Hsz +
                       2 * ((size_t)Hsz * Gsz + WPAD) + XBUF_F) * sizeof(float) +
                      512 * sizeof(int) + Bsz * sizeof(int) + 2048;
  int TC = 16;
  const int cand[7] = {1024, 512, 256, 128, 64, 32, 16};
  for (int i = 0; i < 7; i++) {
    size_t need = fixedBytes + 2 * (size_t)Bsz * cand[i] * Gsz * sizeof(float);
    if (need <= ws_size) { TC = cand[i]; break; }
  }
  int tcShift = 31 - __builtin_clz((unsigned)TC);

  float* Pf    = (float*)d_ws;                      // Bsz*TC*Gsz
  float* Pb    = Pf + (size_t)Bsz * TC * Gsz;       // Bsz*TC*Gsz
  float* zaf   = Pb + (size_t)Bsz * TC * Gsz;       // NTOK
  float* zbf   = zaf + NTOK;
  float* zab   = zbf + NTOK;
  float* zbb   = zab + NTOK;
  float* zp    = zbb + NTOK;
  float* hcF   = zp + NTOK;                         // Bsz*2*Hsz
  float* hcB   = hcF + (size_t)Bsz * 2 * Hsz;
  float* WhhTf = hcB + (size_t)Bsz * 2 * Hsz;       // Hsz*Gsz + WPAD
  float* WhhTb = WhhTf + (size_t)Hsz * Gsz + WPAD;
  float4* xbuf = (float4*)(WhhTb + (size_t)Hsz * Gsz + WPAD);  // 16B aligned
  int*   flags = (int*)((float*)xbuf + XBUF_F);     // 256 ints
  int*   lens  = flags + 256;

  // zero the handshake flags every launch (replay-safe)
  (void)hipMemsetAsync(flags, 0, 256 * sizeof(int), stream);

  k_lengths<<<Bsz, 256, 0, stream>>>(mask, lens);

  const int tgrid = (Gsz * Hsz + 255) / 256;
  k_transpose<<<tgrid, 256, 0, stream>>>(Whh_f, WhhTf);
  k_transpose<<<tgrid, 256, 0, stream>>>(Whh_b, WhhTb);

  int nch = Tsz / TC;
  dim3 gg((Bsz * TC) / BM, Gsz / BN, 2);
  for (int ci = 0; ci < nch; ++ci) {
    int t0f = ci * TC;
    int t0b = (nch - 1 - ci) * TC;
    k_gemm<<<gg, 256, 0, stream>>>(x, embed, Wih_f, b_f, Wih_b, b_b,
                                   Pf, Pb, t0f, t0b, tcShift);
    k_lstm<<<4 * Bsz, 512, 0, stream>>>(Pf, Pb, WhhTf, WhhTb, lens, Wa, Wb,
                                        hcF, hcB, zaf, zbf, zab, zbb,
                                        xbuf, flags, t0f, t0b, TC, ci == 0);
  }

  k_head<<<NTOK / 256, 256, 0, stream>>>(zaf, zbf, zab, zbb, lens, ba, bb, zp);

  (void)hipMemsetAsync(d_out, 0, (size_t)out_size * sizeof(float), stream);
  k_select<<<Bsz, 256, 0, stream>>>(zp, lens, out);
}

// Round 10
// 4621.217 us; speedup vs baseline: 1.5787x; 1.5097x over previous
//
#include <hip/hip_runtime.h>
#include <math.h>

#define Bsz 64
#define Tsz 1024
#define Esz 300
#define Hsz 200
#define Gsz 800   // 4*H
#define NTOK (Bsz*Tsz)
#define WPAD 6400

// NOTE: macro params must not collide with float4 member names x/y/z/w
#define FMA4(A_, W_, H_) do { \
  (A_).x = fmaf((W_).x, (H_), (A_).x); \
  (A_).y = fmaf((W_).y, (H_), (A_).y); \
  (A_).z = fmaf((W_).z, (H_), (A_).z); \
  (A_).w = fmaf((W_).w, (H_), (A_).w); } while (0)

// ---------------- lengths: lens[b] = sum(mask[b,:]) ----------------
// mask may be 1-byte bool or 4-byte int. len >= 512 always, so byte[1]
// is 1 iff 1-byte layout.
__global__ __launch_bounds__(256) void k_lengths(const void* __restrict__ mraw,
                                                 int* __restrict__ lens) {
  __shared__ int red[256];
  const unsigned char* mb = (const unsigned char*)mraw;
  const int isbool = (mb[1] != 0);
  int b = blockIdx.x, tid = threadIdx.x;
  int s = 0;
  if (isbool) {
    const unsigned char* row = mb + (size_t)b * Tsz;
    for (int i = tid; i < Tsz; i += 256) s += (row[i] != 0);
  } else {
    const int* row = (const int*)mraw + (size_t)b * Tsz;
    for (int i = tid; i < Tsz; i += 256) s += (row[i] != 0);
  }
  red[tid] = s; __syncthreads();
  for (int off = 128; off; off >>= 1) {
    if (tid < off) red[tid] += red[tid + off];
    __syncthreads();
  }
  if (tid == 0) lens[b] = red[0];
}

// ---------------- Whh transpose: WhhT[j][r] = Whh[r][j] ----------------
__global__ __launch_bounds__(256) void k_transpose(const float* __restrict__ Whh,
                                                   float* __restrict__ WhhT) {
  int idx = blockIdx.x * 256 + threadIdx.x;
  if (idx >= Gsz * Hsz) return;
  int r = idx / Hsz, j = idx - r * Hsz;
  WhhT[(size_t)j * Gsz + r] = Whh[idx];
}

// ---------------- input projection GEMM, both directions (blockIdx.z) --
#define BM 64
#define BN 160
#define BK 20
__global__ __launch_bounds__(256) void k_gemm(const int* __restrict__ x,
                                              const float* __restrict__ embed,
                                              const float* __restrict__ Wf,
                                              const float* __restrict__ biasf,
                                              const float* __restrict__ Wb_,
                                              const float* __restrict__ biasb,
                                              float* __restrict__ Pf,
                                              float* __restrict__ Pb,
                                              int t0f, int t0b, int tcShift) {
  __shared__ __align__(16) float As[BK][BM];
  __shared__ __align__(16) float Bs[BK][BN];
  __shared__ int toks[BM];
  const int revz = blockIdx.z;
  const float* __restrict__ W    = revz ? Wb_  : Wf;
  const float* __restrict__ bias = revz ? biasb : biasf;
  float* __restrict__ P          = revz ? Pb   : Pf;
  const int t0                   = revz ? t0b  : t0f;
  int tid = threadIdx.x;
  int n0 = blockIdx.x * BM;
  int j0 = blockIdx.y * BN;
  if (tid < BM) {
    int n = n0 + tid;
    int bb = n >> tcShift;
    int tl = n & ((1 << tcShift) - 1);
    toks[tid] = x[(bb << 10) + t0 + tl];
  }
  float acc[8][5];
#pragma unroll
  for (int i = 0; i < 8; i++)
#pragma unroll
    for (int j = 0; j < 5; j++) acc[i][j] = 0.f;
  int rg = tid >> 5;
  int cg = tid & 31;
  for (int k0 = 0; k0 < Esz; k0 += BK) {
    __syncthreads();
    for (int idx = tid; idx < BM * 5; idx += 256) {
      int r = idx / 5, q = idx % 5;
      const float4 v = *reinterpret_cast<const float4*>(
          embed + (size_t)toks[r] * Esz + k0 + q * 4);
      As[q * 4 + 0][r] = v.x; As[q * 4 + 1][r] = v.y;
      As[q * 4 + 2][r] = v.z; As[q * 4 + 3][r] = v.w;
    }
    for (int idx = tid; idx < BN * 5; idx += 256) {
      int j = idx / 5, q = idx % 5;
      const float4 v = *reinterpret_cast<const float4*>(
          W + (size_t)(j0 + j) * Esz + k0 + q * 4);
      Bs[q * 4 + 0][j] = v.x; Bs[q * 4 + 1][j] = v.y;
      Bs[q * 4 + 2][j] = v.z; Bs[q * 4 + 3][j] = v.w;
    }
    __syncthreads();
#pragma unroll
    for (int kk = 0; kk < BK; ++kk) {
      float4 a0 = *reinterpret_cast<const float4*>(&As[kk][rg * 8]);
      float4 a1 = *reinterpret_cast<const float4*>(&As[kk][rg * 8 + 4]);
      float a[8] = {a0.x, a0.y, a0.z, a0.w, a1.x, a1.y, a1.z, a1.w};
      float bv[5];
#pragma unroll
      for (int j = 0; j < 5; j++) bv[j] = Bs[kk][cg + 32 * j];
#pragma unroll
      for (int i = 0; i < 8; i++)
#pragma unroll
        for (int j = 0; j < 5; j++) acc[i][j] = fmaf(a[i], bv[j], acc[i][j]);
    }
  }
#pragma unroll
  for (int j = 0; j < 5; j++) {
    int col = j0 + cg + 32 * j;
    float bb = bias[col];
#pragma unroll
    for (int i = 0; i < 8; i++) {
      int n = n0 + rg * 8 + i;
      P[(size_t)n * Gsz + col] = acc[i][j] + bb;
    }
  }
}

// ---------------- masked LSTM, weights CU-resident ---------------------
// 128 WGs (bid<64 fwd, else bwd), 512 threads (8 waves). Workers tid<500:
// col = tid%100 owns gate-row float4 pair {2col, 2col+1}; gk = tid/100 owns
// k-slice [40gk, 40gk+40). 80 weight-slabs/worker, slab q: row q>>1, col q&1,
// addr wp4[(q>>1)*200 + (q&1)]:
//   slabs [0,40):  VGPR-resident (160 regs, loaded once)
//   slabs [40,57): LDS-resident  (136 KB, [i][tid] layout)
//   slabs [57,80): streamed per step (184 KB/step, 8-deep static ring)
__global__ __launch_bounds__(512, 2) void k_lstm(
    const float* __restrict__ Pf, const float* __restrict__ Pb,
    const float* __restrict__ WhhTf, const float* __restrict__ WhhTb,
    const int* __restrict__ lens,
    const float* __restrict__ Wa, const float* __restrict__ Wb,
    float* __restrict__ hcF, float* __restrict__ hcB,
    float* __restrict__ zaf, float* __restrict__ zbf,
    float* __restrict__ zab, float* __restrict__ zbb,
    int t0f, int t0b, int TC, int init) {
  __shared__ __align__(16) float h[Hsz];
  __shared__ __align__(16) float c[Hsz];
  __shared__ __align__(16) float4 g4[200];      // gates as 200 float4
  __shared__ __align__(16) float4 part[1000];   // [gk][200]
  __shared__ __align__(16) float4 wlds[8500];   // [17][500] resident weights
  __shared__ float redA[4], redB[4];
  int bid = blockIdx.x, tid = threadIdx.x;
  int rev = bid >> 6;
  int b = bid & 63;
  int len = lens[b];
  const float* P    = rev ? Pb : Pf;
  const float* WhhT = rev ? WhhTb : WhhTf;
  float* hcb = (rev ? hcB : hcF) + (size_t)b * 2 * Hsz;
  float* za  = rev ? zab : zaf;
  float* zb  = rev ? zbb : zbf;
  int t0 = rev ? t0b : t0f;
  float wa = 0.f, wb = 0.f;
  if (tid < Hsz) {
    h[tid] = init ? 0.f : hcb[tid];
    c[tid] = init ? 0.f : hcb[Hsz + tid];
    int off = rev ? Hsz : 0;
    wa = Wa[off + tid]; wb = Wb[off + tid];
  }
  const int worker = (tid < 500);
  int col = 0, gk = 0;
  if (worker) { col = tid % 100; gk = tid / 100; }
  const int hbase = gk * 40;
  const float4* __restrict__ wp4 =
      reinterpret_cast<const float4*>(WhhT) + (size_t)hbase * 200 + 2 * col;

  // ---- load persistent weights (once per dispatch) ----
  float4 wreg[40];                       // slabs [0,40)
  if (worker) {
#pragma unroll
    for (int q = 0; q < 40; q++) wreg[q] = wp4[(q >> 1) * 200 + (q & 1)];
#pragma unroll
    for (int i = 0; i < 17; i++)         // slabs [40,57)
      wlds[i * 500 + tid] = wp4[((40 + i) >> 1) * 200 + ((40 + i) & 1)];
  }
  __syncthreads();

  int lo = t0;
  int hi = t0 + TC; if (len < hi) hi = len;
  int nsteps = hi - lo; if (nsteps < 0) nsteps = 0;

  for (int s = 0; s < nsteps; ++s) {
    int t = rev ? (hi - 1 - s) : (lo + s);
    const float4* __restrict__ Prow4 = reinterpret_cast<const float4*>(
        P + ((size_t)b * TC + (t - t0)) * Gsz);
    if (worker) {
      // issue ring slots early (slabs 57..64 in flight during resident fmas)
      float4 rbuf[8];
#pragma unroll
      for (int q = 0; q < 8; q++)
        rbuf[q] = wp4[((57 + q) >> 1) * 200 + ((57 + q) & 1)];
      float4 acc0, acc1;
      if (gk == 0) { acc0 = Prow4[2 * col]; acc1 = Prow4[2 * col + 1]; }
      else {
        acc0.x = acc0.y = acc0.z = acc0.w = 0.f;
        acc1.x = acc1.y = acc1.z = acc1.w = 0.f;
      }
      // phase 1: VGPR-resident slabs [0,40)
#pragma unroll
      for (int u = 0; u < 20; u++) {
        float hj = h[hbase + u];
        FMA4(acc0, wreg[2 * u], hj);
        FMA4(acc1, wreg[2 * u + 1], hj);
      }
      // phase 2: LDS-resident slabs [40,57): row 20+(i>>1), colsel i&1
#pragma unroll
      for (int i = 0; i < 17; i++) {
        float hj = h[hbase + 20 + (i >> 1)];
        float4 wv = wlds[i * 500 + tid];
        if (i & 1) { FMA4(acc1, wv, hj); } else { FMA4(acc0, wv, hj); }
      }
      // phase 3: streamed slabs [57,80), 8-deep static ring (23 slabs)
#pragma unroll
      for (int q = 0; q < 15; q++) {
        float4 wv = rbuf[q & 7];
        rbuf[q & 7] = wp4[((65 + q) >> 1) * 200 + ((65 + q) & 1)];
        float hj = h[hbase + ((57 + q) >> 1)];
        if ((57 + q) & 1) { FMA4(acc1, wv, hj); } else { FMA4(acc0, wv, hj); }
      }
#pragma unroll
      for (int q = 15; q < 23; q++) {
        float4 wv = rbuf[q & 7];
        float hj = h[hbase + ((57 + q) >> 1)];
        if ((57 + q) & 1) { FMA4(acc1, wv, hj); } else { FMA4(acc0, wv, hj); }
      }
      part[gk * 200 + 2 * col]     = acc0;
      part[gk * 200 + 2 * col + 1] = acc1;
    }
    __syncthreads();   // partials ready; h reads complete
    if (tid < 200) {
      float4 p0 = part[tid],       p1 = part[200 + tid], p2 = part[400 + tid];
      float4 p3 = part[600 + tid], p4 = part[800 + tid];
      float4 gg;
      gg.x = p0.x + p1.x + p2.x + p3.x + p4.x;
      gg.y = p0.y + p1.y + p2.y + p3.y + p4.y;
      gg.z = p0.z + p1.z + p2.z + p3.z + p4.z;
      gg.w = p0.w + p1.w + p2.w + p3.w + p4.w;
      g4[tid] = gg;
    }
    __syncthreads();   // g ready
    float pa = 0.f, pb = 0.f;
    if (tid < Hsz) {
      const float* g = reinterpret_cast<const float*>(g4);
      float gi = g[tid], gf = g[Hsz + tid];
      float gc = g[2 * Hsz + tid], go = g[3 * Hsz + tid];
      float ig = 1.f / (1.f + expf(-gi));
      float fg = 1.f / (1.f + expf(-gf));
      float gt = tanhf(gc);
      float og = 1.f / (1.f + expf(-go));
      float cn = fmaf(fg, c[tid], ig * gt);
      float hn = og * tanhf(cn);
      c[tid] = cn; h[tid] = hn;
      pa = hn * wa; pb = hn * wb;
    }
#pragma unroll
    for (int off = 32; off; off >>= 1) {
      pa += __shfl_down(pa, off);
      pb += __shfl_down(pb, off);
    }
    if ((tid & 63) == 0 && tid < 256) { redA[tid >> 6] = pa; redB[tid >> 6] = pb; }
    __syncthreads();   // redA/B ready; h writes visible for next step
    if (tid == 0) {
      float sa = 0.f, sb = 0.f;
#pragma unroll
      for (int w = 0; w < 4; ++w) { sa += redA[w]; sb += redB[w]; }
      za[(size_t)b * Tsz + t] = sa;   // direct store (2 scalars/step)
      zb[(size_t)b * Tsz + t] = sb;
    }
  }
  __syncthreads();
  if (tid < Hsz) { hcb[tid] = h[tid]; hcb[Hsz + tid] = c[tid]; }
}

// ---------------- Kuma head per token (double precision) ---------------
__global__ __launch_bounds__(256) void k_head(const float* __restrict__ zaf,
                                              const float* __restrict__ zbf,
                                              const float* __restrict__ zab,
                                              const float* __restrict__ zbb,
                                              const int* __restrict__ lens,
                                              const float* __restrict__ ba,
                                              const float* __restrict__ bb,
                                              float* __restrict__ zp) {
  int n = blockIdx.x * 256 + threadIdx.x;
  if (n >= NTOK) return;
  int b = n >> 10, t = n & 1023;
  if (t >= lens[b]) { zp[n] = 0.f; return; }
  double av = ((double)zaf[n] + (double)zab[n]) * 100.0 + (double)ba[0];
  double bv = ((double)zbf[n] + (double)zbb[n]) * 100.0 + (double)bb[0];
  double a  = av > 0.0 ? av + log1p(exp(-av)) : log1p(exp(av));
  double bk = bv > 0.0 ? bv + log1p(exp(-bv)) : log1p(exp(bv));
  a  = fmin(fmax(a, 1e-6), 100.0);
  bk = fmin(fmax(bk, 1e-6), 100.0);
  double ia = 1.0 + 1.0 / a;
  double lb = lgamma(ia) + lgamma(bk) - lgamma(ia + bk);
  double mean = bk * exp(lb);
  mean = -0.1 + 1.2 * mean;
  mean = fmin(fmax(mean, 0.0), 1.0);
  zp[n] = (float)mean;
}

// ---------------- stable top-k selection per row -----------------------
__global__ __launch_bounds__(256) void k_select(const float* __restrict__ zp,
                                                const int* __restrict__ lens,
                                                float* __restrict__ out) {
  __shared__ float zv[Tsz];
  __shared__ float wbv[4];
  __shared__ int wbi[4];
  __shared__ int stop;
  int b = blockIdx.x, tid = threadIdx.x;
  const float* row = zp + (size_t)b * Tsz;
  for (int i = tid; i < Tsz; i += 256) zv[i] = row[i];
  if (tid == 0) stop = 0;
  int len = lens[b];
  int k = (int)rintf(0.1f * (float)len);
  __syncthreads();
  for (int it = 0; it < k; ++it) {
    float bvl = -1.f; int bil = 0;
#pragma unroll
    for (int s = 0; s < 4; s++) {
      int i = tid * 4 + s;
      float v = zv[i];
      if (v > bvl) { bvl = v; bil = i; }
    }
    for (int off = 32; off; off >>= 1) {
      float ov = __shfl_down(bvl, off);
      int   oi = __shfl_down(bil, off);
      if (ov > bvl || (ov == bvl && oi < bil)) { bvl = ov; bil = oi; }
    }
    int w = tid >> 6;
    if ((tid & 63) == 0) { wbv[w] = bvl; wbi[w] = bil; }
    __syncthreads();
    if (tid == 0) {
      float fb = wbv[0]; int fi = wbi[0];
      for (int q = 1; q < 4; q++)
        if (wbv[q] > fb || (wbv[q] == fb && wbi[q] < fi)) { fb = wbv[q]; fi = wbi[q]; }
      if (fb <= 0.f) stop = 1;
      else { out[(size_t)b * Tsz + fi] = 1.0f; zv[fi] = -1e30f; }
    }
    __syncthreads();
    if (stop) break;
  }
}

extern "C" void kernel_launch(void* const* d_in, const int* in_sizes, int n_in,
                              void* d_out, int out_size, void* d_ws, size_t ws_size,
                              hipStream_t stream) {
  const int*   x      = (const int*)d_in[0];
  const void*  mask   = d_in[1];
  const float* embed  = (const float*)d_in[2];
  const float* Wih_f  = (const float*)d_in[3];
  const float* Whh_f  = (const float*)d_in[4];
  const float* b_f    = (const float*)d_in[5];
  const float* Wih_b  = (const float*)d_in[6];
  const float* Whh_b  = (const float*)d_in[7];
  const float* b_b    = (const float*)d_in[8];
  const float* Wa     = (const float*)d_in[9];
  const float* ba     = (const float*)d_in[10];
  const float* Wb     = (const float*)d_in[11];
  const float* bb     = (const float*)d_in[12];
  float* out = (float*)d_out;

  // ---- adaptive time-chunk: need TWO P buffers (fwd + bwd) ----
  size_t fixedBytes = (5 * (size_t)NTOK + 2 * (size_t)Bsz * 2 * Hsz +
                       2 * ((size_t)Hsz * Gsz + WPAD)) * sizeof(float) +
                      Bsz * sizeof(int) + 1024;
  int TC = 16;
  const int cand[7] = {1024, 512, 256, 128, 64, 32, 16};
  for (int i = 0; i < 7; i++) {
    size_t need = fixedBytes + 2 * (size_t)Bsz * cand[i] * Gsz * sizeof(float);
    if (need <= ws_size) { TC = cand[i]; break; }
  }
  int tcShift = 31 - __builtin_clz((unsigned)TC);

  float* Pf    = (float*)d_ws;                      // Bsz*TC*Gsz
  float* Pb    = Pf + (size_t)Bsz * TC * Gsz;       // Bsz*TC*Gsz
  float* zaf   = Pb + (size_t)Bsz * TC * Gsz;       // NTOK
  float* zbf   = zaf + NTOK;
  float* zab   = zbf + NTOK;
  float* zbb   = zab + NTOK;
  float* zp    = zbb + NTOK;
  float* hcF   = zp + NTOK;                         // Bsz*2*Hsz
  float* hcB   = hcF + (size_t)Bsz * 2 * Hsz;
  float* WhhTf = hcB + (size_t)Bsz * 2 * Hsz;       // Hsz*Gsz + WPAD
  float* WhhTb = WhhTf + (size_t)Hsz * Gsz + WPAD;
  int*   lens  = (int*)(WhhTb + (size_t)Hsz * Gsz + WPAD);

  k_lengths<<<Bsz, 256, 0, stream>>>(mask, lens);

  const int tgrid = (Gsz * Hsz + 255) / 256;
  k_transpose<<<tgrid, 256, 0, stream>>>(Whh_f, WhhTf);
  k_transpose<<<tgrid, 256, 0, stream>>>(Whh_b, WhhTb);

  int nch = Tsz / TC;
  dim3 gg((Bsz * TC) / BM, Gsz / BN, 2);
  for (int ci = 0; ci < nch; ++ci) {
    int t0f = ci * TC;
    int t0b = (nch - 1 - ci) * TC;
    k_gemm<<<gg, 256, 0, stream>>>(x, embed, Wih_f, b_f, Wih_b, b_b,
                                   Pf, Pb, t0f, t0b, tcShift);
    k_lstm<<<2 * Bsz, 512, 0, stream>>>(Pf, Pb, WhhTf, WhhTb, lens, Wa, Wb,
                                        hcF, hcB, zaf, zbf, zab, zbb,
                                        t0f, t0b, TC, ci == 0);
  }

  k_head<<<NTOK / 256, 256, 0, stream>>>(zaf, zbf, zab, zbb, lens, ba, bb, zp);

  (void)hipMemsetAsync(d_out, 0, (size_t)out_size * sizeof(float), stream);
  k_select<<<Bsz, 256, 0, stream>>>(zp, lens, out);
}

// Round 11
// 4590.973 us; speedup vs baseline: 1.5891x; 1.0066x over previous
//
#include <hip/hip_runtime.h>
#include <math.h>

#define Bsz 64
#define Tsz 1024
#define Esz 300
#define Hsz 200
#define Gsz 800   // 4*H
#define NTOK (Bsz*Tsz)
#define WPAD 6400

// NOTE: macro params must not collide with float4 member names x/y/z/w
#define FMA4(A_, W_, H_) do { \
  (A_).x = fmaf((W_).x, (H_), (A_).x); \
  (A_).y = fmaf((W_).y, (H_), (A_).y); \
  (A_).z = fmaf((W_).z, (H_), (A_).z); \
  (A_).w = fmaf((W_).w, (H_), (A_).w); } while (0)

// ---------------- lengths: lens[b] = sum(mask[b,:]) ----------------
// mask may be 1-byte bool or 4-byte int. len >= 512 always, so byte[1]
// is 1 iff 1-byte layout.
__global__ __launch_bounds__(256) void k_lengths(const void* __restrict__ mraw,
                                                 int* __restrict__ lens) {
  __shared__ int red[256];
  const unsigned char* mb = (const unsigned char*)mraw;
  const int isbool = (mb[1] != 0);
  int b = blockIdx.x, tid = threadIdx.x;
  int s = 0;
  if (isbool) {
    const unsigned char* row = mb + (size_t)b * Tsz;
    for (int i = tid; i < Tsz; i += 256) s += (row[i] != 0);
  } else {
    const int* row = (const int*)mraw + (size_t)b * Tsz;
    for (int i = tid; i < Tsz; i += 256) s += (row[i] != 0);
  }
  red[tid] = s; __syncthreads();
  for (int off = 128; off; off >>= 1) {
    if (tid < off) red[tid] += red[tid + off];
    __syncthreads();
  }
  if (tid == 0) lens[b] = red[0];
}

// ---------------- Whh transpose: WhhT[j][r] = Whh[r][j] ----------------
__global__ __launch_bounds__(256) void k_transpose(const float* __restrict__ Whh,
                                                   float* __restrict__ WhhT) {
  int idx = blockIdx.x * 256 + threadIdx.x;
  if (idx >= Gsz * Hsz) return;
  int r = idx / Hsz, j = idx - r * Hsz;
  WhhT[(size_t)j * Gsz + r] = Whh[idx];
}

// ---------------- input projection GEMM, both directions (blockIdx.z) --
#define BM 64
#define BN 160
#define BK 20
__global__ __launch_bounds__(256) void k_gemm(const int* __restrict__ x,
                                              const float* __restrict__ embed,
                                              const float* __restrict__ Wf,
                                              const float* __restrict__ biasf,
                                              const float* __restrict__ Wb_,
                                              const float* __restrict__ biasb,
                                              float* __restrict__ Pf,
                                              float* __restrict__ Pb,
                                              int t0f, int t0b, int tcShift) {
  __shared__ __align__(16) float As[BK][BM];
  __shared__ __align__(16) float Bs[BK][BN];
  __shared__ int toks[BM];
  const int revz = blockIdx.z;
  const float* __restrict__ W    = revz ? Wb_  : Wf;
  const float* __restrict__ bias = revz ? biasb : biasf;
  float* __restrict__ P          = revz ? Pb   : Pf;
  const int t0                   = revz ? t0b  : t0f;
  int tid = threadIdx.x;
  int n0 = blockIdx.x * BM;
  int j0 = blockIdx.y * BN;
  if (tid < BM) {
    int n = n0 + tid;
    int bb = n >> tcShift;
    int tl = n & ((1 << tcShift) - 1);
    toks[tid] = x[(bb << 10) + t0 + tl];
  }
  float acc[8][5];
#pragma unroll
  for (int i = 0; i < 8; i++)
#pragma unroll
    for (int j = 0; j < 5; j++) acc[i][j] = 0.f;
  int rg = tid >> 5;
  int cg = tid & 31;
  for (int k0 = 0; k0 < Esz; k0 += BK) {
    __syncthreads();
    for (int idx = tid; idx < BM * 5; idx += 256) {
      int r = idx / 5, q = idx % 5;
      const float4 v = *reinterpret_cast<const float4*>(
          embed + (size_t)toks[r] * Esz + k0 + q * 4);
      As[q * 4 + 0][r] = v.x; As[q * 4 + 1][r] = v.y;
      As[q * 4 + 2][r] = v.z; As[q * 4 + 3][r] = v.w;
    }
    for (int idx = tid; idx < BN * 5; idx += 256) {
      int j = idx / 5, q = idx % 5;
      const float4 v = *reinterpret_cast<const float4*>(
          W + (size_t)(j0 + j) * Esz + k0 + q * 4);
      Bs[q * 4 + 0][j] = v.x; Bs[q * 4 + 1][j] = v.y;
      Bs[q * 4 + 2][j] = v.z; Bs[q * 4 + 3][j] = v.w;
    }
    __syncthreads();
#pragma unroll
    for (int kk = 0; kk < BK; ++kk) {
      float4 a0 = *reinterpret_cast<const float4*>(&As[kk][rg * 8]);
      float4 a1 = *reinterpret_cast<const float4*>(&As[kk][rg * 8 + 4]);
      float a[8] = {a0.x, a0.y, a0.z, a0.w, a1.x, a1.y, a1.z, a1.w};
      float bv[5];
#pragma unroll
      for (int j = 0; j < 5; j++) bv[j] = Bs[kk][cg + 32 * j];
#pragma unroll
      for (int i = 0; i < 8; i++)
#pragma unroll
        for (int j = 0; j < 5; j++) acc[i][j] = fmaf(a[i], bv[j], acc[i][j]);
    }
  }
#pragma unroll
  for (int j = 0; j < 5; j++) {
    int col = j0 + cg + 32 * j;
    float bb = bias[col];
#pragma unroll
    for (int i = 0; i < 8; i++) {
      int n = n0 + rg * 8 + i;
      P[(size_t)n * Gsz + col] = acc[i][j] + bb;
    }
  }
}

// ---------------- masked LSTM, weights CU-resident ---------------------
// 128 WGs (bid<64 fwd, else bwd), 512 threads (8 waves). Workers tid<500:
// col = tid%100 owns gate-row float4 pair {2col, 2col+1}; gk = tid/100 owns
// k-slice [40gk, 40gk+40). 80 weight-slabs/worker, slab q: row q>>1, col q&1,
// addr wp4[(q>>1)*200 + (q&1)]:
//   slabs [0,40):  VGPR-resident (160 regs, loaded once)
//   slabs [40,56): LDS-resident  (128 KB, [i][tid] layout)
//   slabs [56,80): streamed, 8-deep CROSS-STEP ring (192 KB/step).
// Ring wraps mod 24: refill r = 56+((q+8)%24); the last 8 refills per step
// are next step's first 8 consumes -> their latency hides under the
// reduce/activation/barrier tail (weights are read-only, so loads may stay
// in flight across __syncthreads legally). 24%8==0 keeps ring phase aligned
// every step with all-compile-time indices.
__global__ __launch_bounds__(512, 2) void k_lstm(
    const float* __restrict__ Pf, const float* __restrict__ Pb,
    const float* __restrict__ WhhTf, const float* __restrict__ WhhTb,
    const int* __restrict__ lens,
    const float* __restrict__ Wa, const float* __restrict__ Wb,
    float* __restrict__ hcF, float* __restrict__ hcB,
    float* __restrict__ zaf, float* __restrict__ zbf,
    float* __restrict__ zab, float* __restrict__ zbb,
    int t0f, int t0b, int TC, int init) {
  __shared__ __align__(16) float h[Hsz];
  __shared__ __align__(16) float c[Hsz];
  __shared__ __align__(16) float4 g4[200];      // gates as 200 float4
  __shared__ __align__(16) float4 part[1000];   // [gk][200]
  __shared__ __align__(16) float4 wlds[8000];   // [16][500] resident weights
  __shared__ float redA[4], redB[4];
  int bid = blockIdx.x, tid = threadIdx.x;
  int rev = bid >> 6;
  int b = bid & 63;
  int len = lens[b];
  const float* P    = rev ? Pb : Pf;
  const float* WhhT = rev ? WhhTb : WhhTf;
  float* hcb = (rev ? hcB : hcF) + (size_t)b * 2 * Hsz;
  float* za  = rev ? zab : zaf;
  float* zb  = rev ? zbb : zbf;
  int t0 = rev ? t0b : t0f;
  float wa = 0.f, wb = 0.f;
  if (tid < Hsz) {
    h[tid] = init ? 0.f : hcb[tid];
    c[tid] = init ? 0.f : hcb[Hsz + tid];
    int off = rev ? Hsz : 0;
    wa = Wa[off + tid]; wb = Wb[off + tid];
  }
  const int worker = (tid < 500);
  int col = 0, gk = 0;
  if (worker) { col = tid % 100; gk = tid / 100; }
  const int hbase = gk * 40;
  const float4* __restrict__ wp4 =
      reinterpret_cast<const float4*>(WhhT) + (size_t)hbase * 200 + 2 * col;

  // ---- load persistent weights (once per dispatch) ----
  float4 wreg[40];                       // slabs [0,40)
  float4 rbuf[8];                        // cross-step stream ring
  if (worker) {
#pragma unroll
    for (int q = 0; q < 40; q++) wreg[q] = wp4[(q >> 1) * 200 + (q & 1)];
#pragma unroll
    for (int i = 0; i < 16; i++)         // slabs [40,56)
      wlds[i * 500 + tid] = wp4[((40 + i) >> 1) * 200 + ((40 + i) & 1)];
    // prologue: fill ring with slabs 56..63
#pragma unroll
    for (int q = 0; q < 8; q++)
      rbuf[q] = wp4[((56 + q) >> 1) * 200 + ((56 + q) & 1)];
  }
  __syncthreads();

  int lo = t0;
  int hi = t0 + TC; if (len < hi) hi = len;
  int nsteps = hi - lo; if (nsteps < 0) nsteps = 0;

  for (int s = 0; s < nsteps; ++s) {
    int t = rev ? (hi - 1 - s) : (lo + s);
    const float4* __restrict__ Prow4 = reinterpret_cast<const float4*>(
        P + ((size_t)b * TC + (t - t0)) * Gsz);
    if (worker) {
      float4 acc0, acc1;
      if (gk == 0) { acc0 = Prow4[2 * col]; acc1 = Prow4[2 * col + 1]; }
      else {
        acc0.x = acc0.y = acc0.z = acc0.w = 0.f;
        acc1.x = acc1.y = acc1.z = acc1.w = 0.f;
      }
      // phase 1: VGPR-resident slabs [0,40)
#pragma unroll
      for (int u = 0; u < 20; u++) {
        float hj = h[hbase + u];
        FMA4(acc0, wreg[2 * u], hj);
        FMA4(acc1, wreg[2 * u + 1], hj);
      }
      // phase 2: LDS-resident slabs [40,56): row 20+(i>>1), accsel i&1
#pragma unroll
      for (int i = 0; i < 16; i++) {
        float hj = h[hbase + 20 + (i >> 1)];
        float4 wv = wlds[i * 500 + tid];
        if (i & 1) { FMA4(acc1, wv, hj); } else { FMA4(acc0, wv, hj); }
      }
      // phase 3: streamed slabs [56,80), steady-state cross-step ring.
      // consume slab 56+q from rbuf[q&7]; refill slab 56+((q+8)%24).
      // Refills for q>=16 are next step's slabs 56..63 (land during tail).
#pragma unroll
      for (int q = 0; q < 24; q++) {
        float4 wv = rbuf[q & 7];
        const int r = 56 + ((q + 8) % 24);
        rbuf[q & 7] = wp4[(r >> 1) * 200 + (r & 1)];
        float hj = h[hbase + 28 + (q >> 1)];
        if (q & 1) { FMA4(acc1, wv, hj); } else { FMA4(acc0, wv, hj); }
      }
      part[gk * 200 + 2 * col]     = acc0;
      part[gk * 200 + 2 * col + 1] = acc1;
    }
    __syncthreads();   // partials ready; h reads complete
    if (tid < 200) {
      float4 p0 = part[tid],       p1 = part[200 + tid], p2 = part[400 + tid];
      float4 p3 = part[600 + tid], p4 = part[800 + tid];
      float4 gg;
      gg.x = p0.x + p1.x + p2.x + p3.x + p4.x;
      gg.y = p0.y + p1.y + p2.y + p3.y + p4.y;
      gg.z = p0.z + p1.z + p2.z + p3.z + p4.z;
      gg.w = p0.w + p1.w + p2.w + p3.w + p4.w;
      g4[tid] = gg;
    }
    __syncthreads();   // g ready
    float pa = 0.f, pb = 0.f;
    if (tid < Hsz) {
      const float* g = reinterpret_cast<const float*>(g4);
      float gi = g[tid], gf = g[Hsz + tid];
      float gc = g[2 * Hsz + tid], go = g[3 * Hsz + tid];
      float ig = 1.f / (1.f + expf(-gi));
      float fg = 1.f / (1.f + expf(-gf));
      float gt = tanhf(gc);
      float og = 1.f / (1.f + expf(-go));
      float cn = fmaf(fg, c[tid], ig * gt);
      float hn = og * tanhf(cn);
      c[tid] = cn; h[tid] = hn;
      pa = hn * wa; pb = hn * wb;
    }
#pragma unroll
    for (int off = 32; off; off >>= 1) {
      pa += __shfl_down(pa, off);
      pb += __shfl_down(pb, off);
    }
    if ((tid & 63) == 0 && tid < 256) { redA[tid >> 6] = pa; redB[tid >> 6] = pb; }
    __syncthreads();   // redA/B ready; h writes visible for next step
    if (tid == 0) {
      float sa = 0.f, sb = 0.f;
#pragma unroll
      for (int w = 0; w < 4; ++w) { sa += redA[w]; sb += redB[w]; }
      za[(size_t)b * Tsz + t] = sa;   // direct store (2 scalars/step)
      zb[(size_t)b * Tsz + t] = sb;
    }
  }
  __syncthreads();
  if (tid < Hsz) { hcb[tid] = h[tid]; hcb[Hsz + tid] = c[tid]; }
}

// ---------------- Kuma head per token (double precision) ---------------
__global__ __launch_bounds__(256) void k_head(const float* __restrict__ zaf,
                                              const float* __restrict__ zbf,
                                              const float* __restrict__ zab,
                                              const float* __restrict__ zbb,
                                              const int* __restrict__ lens,
                                              const float* __restrict__ ba,
                                              const float* __restrict__ bb,
                                              float* __restrict__ zp) {
  int n = blockIdx.x * 256 + threadIdx.x;
  if (n >= NTOK) return;
  int b = n >> 10, t = n & 1023;
  if (t >= lens[b]) { zp[n] = 0.f; return; }
  double av = ((double)zaf[n] + (double)zab[n]) * 100.0 + (double)ba[0];
  double bv = ((double)zbf[n] + (double)zbb[n]) * 100.0 + (double)bb[0];
  double a  = av > 0.0 ? av + log1p(exp(-av)) : log1p(exp(av));
  double bk = bv > 0.0 ? bv + log1p(exp(-bv)) : log1p(exp(bv));
  a  = fmin(fmax(a, 1e-6), 100.0);
  bk = fmin(fmax(bk, 1e-6), 100.0);
  double ia = 1.0 + 1.0 / a;
  double lb = lgamma(ia) + lgamma(bk) - lgamma(ia + bk);
  double mean = bk * exp(lb);
  mean = -0.1 + 1.2 * mean;
  mean = fmin(fmax(mean, 0.0), 1.0);
  zp[n] = (float)mean;
}

// ---------------- stable top-k selection per row -----------------------
__global__ __launch_bounds__(256) void k_select(const float* __restrict__ zp,
                                                const int* __restrict__ lens,
                                                float* __restrict__ out) {
  __shared__ float zv[Tsz];
  __shared__ float wbv[4];
  __shared__ int wbi[4];
  __shared__ int stop;
  int b = blockIdx.x, tid = threadIdx.x;
  const float* row = zp + (size_t)b * Tsz;
  for (int i = tid; i < Tsz; i += 256) zv[i] = row[i];
  if (tid == 0) stop = 0;
  int len = lens[b];
  int k = (int)rintf(0.1f * (float)len);
  __syncthreads();
  for (int it = 0; it < k; ++it) {
    float bvl = -1.f; int bil = 0;
#pragma unroll
    for (int s = 0; s < 4; s++) {
      int i = tid * 4 + s;
      float v = zv[i];
      if (v > bvl) { bvl = v; bil = i; }
    }
    for (int off = 32; off; off >>= 1) {
      float ov = __shfl_down(bvl, off);
      int   oi = __shfl_down(bil, off);
      if (ov > bvl || (ov == bvl && oi < bil)) { bvl = ov; bil = oi; }
    }
    int w = tid >> 6;
    if ((tid & 63) == 0) { wbv[w] = bvl; wbi[w] = bil; }
    __syncthreads();
    if (tid == 0) {
      float fb = wbv[0]; int fi = wbi[0];
      for (int q = 1; q < 4; q++)
        if (wbv[q] > fb || (wbv[q] == fb && wbi[q] < fi)) { fb = wbv[q]; fi = wbi[q]; }
      if (fb <= 0.f) stop = 1;
      else { out[(size_t)b * Tsz + fi] = 1.0f; zv[fi] = -1e30f; }
    }
    __syncthreads();
    if (stop) break;
  }
}

extern "C" void kernel_launch(void* const* d_in, const int* in_sizes, int n_in,
                              void* d_out, int out_size, void* d_ws, size_t ws_size,
                              hipStream_t stream) {
  const int*   x      = (const int*)d_in[0];
  const void*  mask   = d_in[1];
  const float* embed  = (const float*)d_in[2];
  const float* Wih_f  = (const float*)d_in[3];
  const float* Whh_f  = (const float*)d_in[4];
  const float* b_f    = (const float*)d_in[5];
  const float* Wih_b  = (const float*)d_in[6];
  const float* Whh_b  = (const float*)d_in[7];
  const float* b_b    = (const float*)d_in[8];
  const float* Wa     = (const float*)d_in[9];
  const float* ba     = (const float*)d_in[10];
  const float* Wb     = (const float*)d_in[11];
  const float* bb     = (const float*)d_in[12];
  float* out = (float*)d_out;

  // ---- adaptive time-chunk: need TWO P buffers (fwd + bwd) ----
  size_t fixedBytes = (5 * (size_t)NTOK + 2 * (size_t)Bsz * 2 * Hsz +
                       2 * ((size_t)Hsz * Gsz + WPAD)) * sizeof(float) +
                      Bsz * sizeof(int) + 1024;
  int TC = 16;
  const int cand[7] = {1024, 512, 256, 128, 64, 32, 16};
  for (int i = 0; i < 7; i++) {
    size_t need = fixedBytes + 2 * (size_t)Bsz * cand[i] * Gsz * sizeof(float);
    if (need <= ws_size) { TC = cand[i]; break; }
  }
  int tcShift = 31 - __builtin_clz((unsigned)TC);

  float* Pf    = (float*)d_ws;                      // Bsz*TC*Gsz
  float* Pb    = Pf + (size_t)Bsz * TC * Gsz;       // Bsz*TC*Gsz
  float* zaf   = Pb + (size_t)Bsz * TC * Gsz;       // NTOK
  float* zbf   = zaf + NTOK;
  float* zab   = zbf + NTOK;
  float* zbb   = zab + NTOK;
  float* zp    = zbb + NTOK;
  float* hcF   = zp + NTOK;                         // Bsz*2*Hsz
  float* hcB   = hcF + (size_t)Bsz * 2 * Hsz;
  float* WhhTf = hcB + (size_t)Bsz * 2 * Hsz;       // Hsz*Gsz + WPAD
  float* WhhTb = WhhTf + (size_t)Hsz * Gsz + WPAD;
  int*   lens  = (int*)(WhhTb + (size_t)Hsz * Gsz + WPAD);

  k_lengths<<<Bsz, 256, 0, stream>>>(mask, lens);

  const int tgrid = (Gsz * Hsz + 255) / 256;
  k_transpose<<<tgrid, 256, 0, stream>>>(Whh_f, WhhTf);
  k_transpose<<<tgrid, 256, 0, stream>>>(Whh_b, WhhTb);

  int nch = Tsz / TC;
  dim3 gg((Bsz * TC) / BM, Gsz / BN, 2);
  for (int ci = 0; ci < nch; ++ci) {
    int t0f = ci * TC;
    int t0b = (nch - 1 - ci) * TC;
    k_gemm<<<gg, 256, 0, stream>>>(x, embed, Wih_f, b_f, Wih_b, b_b,
                                   Pf, Pb, t0f, t0b, tcShift);
    k_lstm<<<2 * Bsz, 512, 0, stream>>>(Pf, Pb, WhhTf, WhhTb, lens, Wa, Wb,
                                        hcF, hcB, zaf, zbf, zab, zbb,
                                        t0f, t0b, TC, ci == 0);
  }

  k_head<<<NTOK / 256, 256, 0, stream>>>(zaf, zbf, zab, zbb, lens, ba, bb, zp);

  (void)hipMemsetAsync(d_out, 0, (size_t)out_size * sizeof(float), stream);
  k_select<<<Bsz, 256, 0, stream>>>(zp, lens, out);
}